// Round 5
// baseline (287.768 us; speedup 1.0000x reference)
//
#include <hip/hip_runtime.h>
#include <hip/hip_bf16.h>
#include <math.h>

// Problem constants (from reference)
#define FEAT 128
#define HID 64
#define LAT 32
#define NG 64
#define MAXN 30
#define SCAN_CHUNK 512
#define NPART 8
// out layout: adj (30*30=900) | mu (64*32=2048) | logvar (2048)

__global__ void k_zero_i(int* p, int n) {
    int i = blockIdx.x * blockDim.x + threadIdx.x;
    if (i < n) p[i] = 0;
}

__global__ void k_zero_f(float* p, int n) {
    int i = blockIdx.x * blockDim.x + threadIdx.x;
    if (i < n) p[i] = 0.0f;
}

// Partitioned in-degree histogram: partition p = blockIdx&7 (-> XCD p by
// round-robin dispatch) owns dst range [base, base+psize). LDS histogram,
// then coalesced atomic merge into the dense global range.
__global__ __launch_bounds__(256) void k_hist_part(const int* __restrict__ dst,
                                                   int* __restrict__ hist,
                                                   int N, int E) {
    __shared__ int lh[6400];  // >= ceil(N/8) = 6250
    int part = blockIdx.x & (NPART - 1);
    int psz0 = (N + NPART - 1) / NPART;
    int base = part * psz0;
    int psize = min(psz0, N - base);
    for (int i = threadIdx.x; i < psize; i += 256) lh[i] = 0;
    __syncthreads();
    int bpp = gridDim.x >> 3;
    int bi = blockIdx.x >> 3;
    for (long e = (long)bi * 256 + threadIdx.x; e < E; e += (long)bpp * 256) {
        int r = dst[e] - base;
        if ((unsigned)r < (unsigned)psize) atomicAdd(&lh[r], 1);
    }
    __syncthreads();
    for (int i = threadIdx.x; i < psize; i += 256) {
        int v = lh[i];
        if (v) atomicAdd(&hist[base + i], v);
    }
}

// block-level inclusive scan (Hillis-Steele), chunk = 512
__global__ __launch_bounds__(SCAN_CHUNK) void k_scan1(const int* __restrict__ hist,
                                                      int* __restrict__ incl,
                                                      int* __restrict__ bsum, int N) {
    __shared__ int buf[SCAN_CHUNK];
    int i = blockIdx.x * SCAN_CHUNK + threadIdx.x;
    int v = (i < N) ? hist[i] : 0;
    buf[threadIdx.x] = v;
    __syncthreads();
    for (int d = 1; d < SCAN_CHUNK; d <<= 1) {
        int t = (threadIdx.x >= d) ? buf[threadIdx.x - d] : 0;
        __syncthreads();
        buf[threadIdx.x] += t;
        __syncthreads();
    }
    if (i < N) incl[i] = buf[threadIdx.x];
    if (threadIdx.x == SCAN_CHUNK - 1) bsum[blockIdx.x] = buf[threadIdx.x];
}

// scan of block sums (single block, up to 128 blocks) -> exclusive
__global__ __launch_bounds__(128) void k_scan_top(int* bsum, int nb) {
    __shared__ int buf[128];
    int v = (threadIdx.x < nb) ? bsum[threadIdx.x] : 0;
    buf[threadIdx.x] = v;
    __syncthreads();
    for (int d = 1; d < 128; d <<= 1) {
        int t = (threadIdx.x >= d) ? buf[threadIdx.x - d] : 0;
        __syncthreads();
        buf[threadIdx.x] += t;
        __syncthreads();
    }
    if (threadIdx.x < nb) bsum[threadIdx.x] = buf[threadIdx.x] - v;  // exclusive
}

// finalize: exclusive offsets, cursor copy, dinv = rsqrt(1 + indeg)
__global__ void k_scan_add(const int* __restrict__ hist, const int* __restrict__ incl,
                           const int* __restrict__ bsum, int* __restrict__ off,
                           int* __restrict__ cursor, float* __restrict__ dinv,
                           int N, int E) {
    int i = blockIdx.x * blockDim.x + threadIdx.x;
    if (i < N) {
        int h = hist[i];
        int o = incl[i] - h + bsum[i / SCAN_CHUNK];
        off[i] = o;
        cursor[i] = o;
        dinv[i] = rsqrtf(1.0f + (float)h);
    }
    if (i == 0) off[N] = E;
}

// Partitioned bucket-fill: partition p (blockIdx&7 -> XCD p) handles dsts in
// its range only; CSR ssrc region for that range is written by one XCD only
// -> lines fill densely in that XCD's L2, no cross-XCD write ping-pong.
__global__ __launch_bounds__(256) void k_sortedges_part(const int* __restrict__ src,
                                                        const int* __restrict__ dst,
                                                        int* __restrict__ cursor,
                                                        int* __restrict__ ssrc,
                                                        int N, int E) {
    int part = blockIdx.x & (NPART - 1);
    int psz0 = (N + NPART - 1) / NPART;
    int base = part * psz0;
    int psize = min(psz0, N - base);
    int bpp = gridDim.x >> 3;
    int bi = blockIdx.x >> 3;
    for (long e = (long)bi * 256 + threadIdx.x; e < E; e += (long)bpp * 256) {
        int d = dst[e];
        int r = d - base;
        if ((unsigned)r < (unsigned)psize) {
            int pos = atomicAdd(&cursor[d], 1);
            ssrc[pos] = src[e];
        }
    }
}

// GEMM: hw = in @ W  (N x K @ K x 64). One wave per row; W staged in LDS.
template <int K>
__global__ __launch_bounds__(256) void k_gemm(const float* __restrict__ in,
                                              const float* __restrict__ W,
                                              float* __restrict__ hw, int N) {
    __shared__ float Wl[K * 64];
    __shared__ float xr[4][K];
    int tid = threadIdx.x;
    for (int i = tid; i < K * 64; i += 256) Wl[i] = W[i];
    __syncthreads();
    int lane = tid & 63;
    int wv = tid >> 6;
    int stride = gridDim.x * 4;
    for (int row = blockIdx.x * 4 + wv; row < N; row += stride) {
        for (int k = lane; k < K; k += 64) xr[wv][k] = in[(long)row * K + k];
        float acc = 0.0f;
#pragma unroll
        for (int k = 0; k < K; ++k) acc += xr[wv][k] * Wl[k * 64 + lane];
        hw[(long)row * 64 + lane] = acc;
    }
}

// CSR gather: out[d] = sum_in-edges hw[s]*dinv[s]*dinv[d] + hw[d]*snorm + b
// (+optional relu). One wave per dst node; lane = feature. dinv[s] is a
// lane-uniform broadcast load (dinv: 200KB, L2-resident).
__global__ __launch_bounds__(256) void k_gather(const float* __restrict__ hw,
                                                const int* __restrict__ ssrc,
                                                const int* __restrict__ off,
                                                const float* __restrict__ dinv,
                                                const float* __restrict__ b,
                                                float* __restrict__ outb,
                                                int N, int do_relu) {
    int wid = blockIdx.x * 4 + (threadIdx.x >> 6);
    int lane = threadIdx.x & 63;
    if (wid >= N) return;
    int j0 = off[wid], j1 = off[wid + 1];
    float di = dinv[wid];
    float acc0 = hw[(long)wid * 64 + lane] * (di * di) + b[lane];
    float acc1 = 0.0f;
    int j = j0;
    for (; j + 3 < j1; j += 4) {
        int s0 = ssrc[j], s1 = ssrc[j + 1], s2 = ssrc[j + 2], s3 = ssrc[j + 3];
        float d0 = dinv[s0], d1 = dinv[s1], d2 = dinv[s2], d3 = dinv[s3];
        float v0 = hw[(long)s0 * 64 + lane];
        float v1 = hw[(long)s1 * 64 + lane];
        float v2 = hw[(long)s2 * 64 + lane];
        float v3 = hw[(long)s3 * 64 + lane];
        acc0 += v0 * (d0 * di);
        acc1 += v1 * (d1 * di);
        acc0 += v2 * (d2 * di);
        acc1 += v3 * (d3 * di);
    }
    for (; j < j1; ++j) {
        int s = ssrc[j];
        acc0 += hw[(long)s * 64 + lane] * (dinv[s] * di);
    }
    float acc = acc0 + acc1;
    if (do_relu) acc = fmaxf(acc, 0.0f);
    outb[(long)wid * 64 + lane] = acc;
}

// relu + mean-pool: batch is SORTED; each wave owns a contiguous node range,
// register-accumulates, flushes one atomicAdd per graph transition.
__global__ __launch_bounds__(256) void k_relu_pool(const float* __restrict__ agg,
                                                   const int* __restrict__ batch,
                                                   float* __restrict__ pooled,
                                                   float* __restrict__ counts,
                                                   int N, int rows_per_wave) {
    int wid = blockIdx.x * (blockDim.x >> 6) + (threadIdx.x >> 6);
    int lane = threadIdx.x & 63;
    int i0 = wid * rows_per_wave;
    if (i0 >= N) return;
    int i1 = min(i0 + rows_per_wave, N);
    int cur = batch[i0];
    float acc = 0.0f, cnt = 0.0f;
    for (int i = i0; i < i1; ++i) {
        int g = batch[i];
        if (g != cur) {
            atomicAdd(&pooled[cur * 64 + lane], acc);
            if (lane == 0) atomicAdd(&counts[cur], cnt);
            acc = 0.0f; cnt = 0.0f; cur = g;
        }
        acc += fmaxf(agg[(long)i * 64 + lane], 0.0f);
        cnt += 1.0f;
    }
    atomicAdd(&pooled[cur * 64 + lane], acc);
    if (lane == 0) atomicAdd(&counts[cur], cnt);
}

__global__ void k_pool_div(float* pooled, const float* counts) {
    int i = blockIdx.x * blockDim.x + threadIdx.x;
    if (i < NG * HID) {
        float c = fmaxf(counts[i >> 6], 1.0f);
        pooled[i] /= c;
    }
}

// mu / logvar heads -> out[900 + idx]
__global__ void k_heads(const float* __restrict__ pooled,
                        const float* __restrict__ Wmu, const float* __restrict__ bmu,
                        const float* __restrict__ Wlv, const float* __restrict__ blv,
                        float* __restrict__ out) {
    int idx = blockIdx.x * blockDim.x + threadIdx.x;
    if (idx >= 2 * NG * LAT) return;
    int which = idx >> 11;          // 0: mu, 1: logvar
    int r = idx & (NG * LAT - 1);
    int g = r >> 5, l = r & 31;
    const float* W = which ? Wlv : Wmu;
    const float* b = which ? blv : bmu;
    float s = b[l];
#pragma unroll 8
    for (int h = 0; h < HID; ++h) s += pooled[g * 64 + h] * W[h * 32 + l];
    out[900 + idx] = s;
}

// Decoder stage 1: 30 blocks x 64 threads; parallelizes Wl2/We1 reads.
__global__ __launch_bounds__(64) void k_dec1(const float* __restrict__ Wl1,
                                             const float* __restrict__ bl1,
                                             const float* __restrict__ Wl2,
                                             const float* __restrict__ bl2,
                                             const float* __restrict__ We1,
                                             const float* __restrict__ out,
                                             float* __restrict__ hi,
                                             float* __restrict__ hj) {
    __shared__ float z0[LAT];
    __shared__ float hr[HID];
    __shared__ float em[HID];
    int tid = threadIdx.x;
    int n = blockIdx.x;
    if (tid < LAT) z0[tid] = out[900 + tid];  // mu row of graph 0
    __syncthreads();
    float s = bl1[tid];
#pragma unroll
    for (int l = 0; l < LAT; ++l) s += z0[l] * Wl1[l * HID + tid];
    hr[tid] = fmaxf(s, 0.0f);
    __syncthreads();
    float e = bl2[n * HID + tid];
#pragma unroll 8
    for (int h = 0; h < HID; ++h) e += hr[h] * Wl2[h * (HID * MAXN) + n * HID + tid];
    em[tid] = e;
    __syncthreads();
    float a = 0.0f, bb = 0.0f;
#pragma unroll 8
    for (int f = 0; f < HID; ++f) {
        float ev = em[f];
        a += ev * We1[f * HID + tid];
        bb += ev * We1[(HID + f) * HID + tid];
    }
    hi[n * HID + tid] = a;
    hj[n * HID + tid] = bb;
}

// Decoder stage 2: single block, adj from LDS-staged hi/hj (stride-65 pad).
__global__ __launch_bounds__(256) void k_dec2(const float* __restrict__ hi,
                                              const float* __restrict__ hj,
                                              const float* __restrict__ be1,
                                              const float* __restrict__ We2,
                                              const float* __restrict__ be2,
                                              float* __restrict__ out) {
    __shared__ float shi[MAXN * 65];
    __shared__ float shj[MAXN * 65];
    __shared__ float sbe[HID];
    __shared__ float sw[HID];
    int tid = threadIdx.x;
    for (int i = tid; i < MAXN * HID; i += 256) {
        int n = i >> 6, k = i & 63;
        shi[n * 65 + k] = hi[i];
        shj[n * 65 + k] = hj[i];
    }
    if (tid < HID) { sbe[tid] = be1[tid]; sw[tid] = We2[tid]; }
    __syncthreads();
    float bias2 = be2[0];
    for (int idx = tid; idx < MAXN * MAXN; idx += 256) {
        int i = idx / MAXN, j = idx % MAXN;
        if (i == j) { out[idx] = 0.0f; continue; }
        int a = i < j ? i : j;
        int b = i < j ? j : i;
        float s = bias2;
#pragma unroll 8
        for (int k = 0; k < HID; ++k)
            s += fmaxf(shi[a * 65 + k] + shj[b * 65 + k] + sbe[k], 0.0f) * sw[k];
        out[idx] = 1.0f / (1.0f + expf(-s));
    }
}

extern "C" void kernel_launch(void* const* d_in, const int* in_sizes, int n_in,
                              void* d_out, int out_size, void* d_ws, size_t ws_size,
                              hipStream_t stream) {
    const float* x = (const float*)d_in[0];
    const int* ei = (const int*)d_in[1];
    const int* batch = (const int*)d_in[2];
    const float* W1 = (const float*)d_in[4];
    const float* b1 = (const float*)d_in[5];
    const float* W2 = (const float*)d_in[6];
    const float* b2 = (const float*)d_in[7];
    const float* Wmu = (const float*)d_in[8];
    const float* bmu = (const float*)d_in[9];
    const float* Wlv = (const float*)d_in[10];
    const float* blv = (const float*)d_in[11];
    const float* Wl1 = (const float*)d_in[12];
    const float* bl1 = (const float*)d_in[13];
    const float* Wl2 = (const float*)d_in[14];
    const float* bl2 = (const float*)d_in[15];
    const float* We1 = (const float*)d_in[16];
    const float* be1 = (const float*)d_in[17];
    const float* We2 = (const float*)d_in[18];
    const float* be2 = (const float*)d_in[19];

    const int N = in_sizes[2];            // 50000
    const int E = in_sizes[1] / 2;        // 800000
    const int* src = ei;
    const int* dst = ei + E;

    // workspace carve-up, 256B aligned
    char* ws = (char*)d_ws;
    size_t off_b = 0;
    auto alloc = [&](size_t nbytes) {
        void* p = (void*)(ws + off_b);
        off_b = (off_b + nbytes + 255) & ~(size_t)255;
        return p;
    };
    float* dinv   = (float*)alloc((size_t)N * 4);
    float* bufA   = (float*)alloc((size_t)N * 64 * 4);  // h1 / agg2
    float* bufB   = (float*)alloc((size_t)N * 64 * 4);  // hw1 / hw2
    float* pooled = (float*)alloc((NG * HID + NG) * 4); // pooled | counts contiguous
    float* counts = pooled + NG * HID;
    int*   hist   = (int*)alloc((size_t)N * 4);
    int*   incl   = (int*)alloc((size_t)N * 4);
    int*   bsum   = (int*)alloc(128 * 4);
    int*   offs   = (int*)alloc(((size_t)N + 1) * 4);
    int*   cursor = (int*)alloc((size_t)N * 4);
    int*   ssrc   = (int*)alloc((size_t)E * 4);
    float* dhi    = (float*)alloc(MAXN * HID * 4);
    float* dhj    = (float*)alloc(MAXN * HID * 4);

    float* out = (float*)d_out;
    const int nb_scan = (N + SCAN_CHUNK - 1) / SCAN_CHUNK;  // 98

    // 1) CSR build: hist -> scan -> offsets/dinv -> partitioned bucket fill
    k_zero_i<<<(N + 255) / 256, 256, 0, stream>>>(hist, N);
    k_hist_part<<<128, 256, 0, stream>>>(dst, hist, N, E);
    k_scan1<<<nb_scan, SCAN_CHUNK, 0, stream>>>(hist, incl, bsum, N);
    k_scan_top<<<1, 128, 0, stream>>>(bsum, nb_scan);
    k_scan_add<<<(N + 255) / 256, 256, 0, stream>>>(hist, incl, bsum, offs, cursor, dinv, N, E);
    k_sortedges_part<<<512, 256, 0, stream>>>(src, dst, cursor, ssrc, N, E);

    // zero pooled + counts (contiguous)
    k_zero_f<<<(NG * HID + NG + 255) / 256, 256, 0, stream>>>(pooled, NG * HID + NG);

    // 2) layer 1: hw1 = x@W1 ; h1 = relu(gather)
    k_gemm<FEAT><<<2048, 256, 0, stream>>>(x, W1, bufB, N);
    k_gather<<<(N + 3) / 4, 256, 0, stream>>>(bufB, ssrc, offs, dinv, b1, bufA, N, 1);

    // 3) layer 2: hw2 = h1@W2 ; agg2 = gather (relu deferred to pool)
    k_gemm<HID><<<2048, 256, 0, stream>>>(bufA, W2, bufB, N);
    k_gather<<<(N + 3) / 4, 256, 0, stream>>>(bufB, ssrc, offs, dinv, b2, bufA, N, 0);

    // 4) relu + mean-pool (contiguous ranges, register accumulation)
    {
        const int waves = 2048;
        int rpw = (N + waves - 1) / waves;
        k_relu_pool<<<512, 256, 0, stream>>>(bufA, batch, pooled, counts, N, rpw);
    }
    k_pool_div<<<(NG * HID + 255) / 256, 256, 0, stream>>>(pooled, counts);

    // 5) mu / logvar -> out[900:]
    k_heads<<<(2 * NG * LAT + 255) / 256, 256, 0, stream>>>(pooled, Wmu, bmu, Wlv, blv, out);

    // 6) decoder -> out[0:900]
    k_dec1<<<MAXN, 64, 0, stream>>>(Wl1, bl1, Wl2, bl2, We1, out, dhi, dhj);
    k_dec2<<<1, 256, 0, stream>>>(dhi, dhj, be1, We2, be2, out);
}

// Round 6
// 259.801 us; speedup vs baseline: 1.1076x; 1.1076x over previous
//
#include <hip/hip_runtime.h>
#include <hip/hip_bf16.h>
#include <math.h>

// Problem constants (from reference)
#define FEAT 128
#define HID 64
#define LAT 32
#define NG 64
#define MAXN 30
#define SCAN_CHUNK 512
#define NPART 8
// out layout: adj (30*30=900) | mu (64*32=2048) | logvar (2048)

__global__ void k_zero_i(int* p, int n) {
    int i = blockIdx.x * blockDim.x + threadIdx.x;
    if (i < n) p[i] = 0;
}

__global__ void k_zero_f(float* p, int n) {
    int i = blockIdx.x * blockDim.x + threadIdx.x;
    if (i < n) p[i] = 0.0f;
}

// Partitioned in-degree histogram, DIRECT global atomics (no LDS):
// partition p = blockIdx&7 -> XCD p by round-robin dispatch; p owns dst range
// [base,lim). hist lines for that range are only RMW'd by one XCD -> no
// cross-XCD line bouncing. Cost: 8x redundant dst reads (L2/L3-served).
__global__ __launch_bounds__(256) void k_hist_part(const int* __restrict__ dst,
                                                   int* __restrict__ hist,
                                                   int N, int E) {
    int part = blockIdx.x & (NPART - 1);
    int psz0 = (N + NPART - 1) / NPART;
    int base = part * psz0;
    int lim = min(base + psz0, N);
    int bpp = gridDim.x >> 3;
    int bi = blockIdx.x >> 3;
    for (long e = (long)bi * 256 + threadIdx.x; e < E; e += (long)bpp * 256) {
        int d = dst[e];
        if (d >= base && d < lim) atomicAdd(&hist[d], 1);
    }
}

// block-level inclusive scan (Hillis-Steele), chunk = 512
__global__ __launch_bounds__(SCAN_CHUNK) void k_scan1(const int* __restrict__ hist,
                                                      int* __restrict__ incl,
                                                      int* __restrict__ bsum, int N) {
    __shared__ int buf[SCAN_CHUNK];
    int i = blockIdx.x * SCAN_CHUNK + threadIdx.x;
    int v = (i < N) ? hist[i] : 0;
    buf[threadIdx.x] = v;
    __syncthreads();
    for (int d = 1; d < SCAN_CHUNK; d <<= 1) {
        int t = (threadIdx.x >= d) ? buf[threadIdx.x - d] : 0;
        __syncthreads();
        buf[threadIdx.x] += t;
        __syncthreads();
    }
    if (i < N) incl[i] = buf[threadIdx.x];
    if (threadIdx.x == SCAN_CHUNK - 1) bsum[blockIdx.x] = buf[threadIdx.x];
}

// scan of block sums (single block, up to 128 blocks) -> exclusive
__global__ __launch_bounds__(128) void k_scan_top(int* bsum, int nb) {
    __shared__ int buf[128];
    int v = (threadIdx.x < nb) ? bsum[threadIdx.x] : 0;
    buf[threadIdx.x] = v;
    __syncthreads();
    for (int d = 1; d < 128; d <<= 1) {
        int t = (threadIdx.x >= d) ? buf[threadIdx.x - d] : 0;
        __syncthreads();
        buf[threadIdx.x] += t;
        __syncthreads();
    }
    if (threadIdx.x < nb) bsum[threadIdx.x] = buf[threadIdx.x] - v;  // exclusive
}

// finalize: exclusive offsets, cursor copy, dinv = rsqrt(1 + indeg)
__global__ void k_scan_add(const int* __restrict__ hist, const int* __restrict__ incl,
                           const int* __restrict__ bsum, int* __restrict__ off,
                           int* __restrict__ cursor, float* __restrict__ dinv,
                           int N, int E) {
    int i = blockIdx.x * blockDim.x + threadIdx.x;
    if (i < N) {
        int h = hist[i];
        int o = incl[i] - h + bsum[i / SCAN_CHUNK];
        off[i] = o;
        cursor[i] = o;
        dinv[i] = rsqrtf(1.0f + (float)h);
    }
    if (i == 0) off[N] = E;
}

// Partitioned bucket-fill: partition p (blockIdx&7 -> XCD p) handles dsts in
// its range only; CSR ssrc region for that range is written by one XCD only
// -> lines fill densely in that XCD's L2, no cross-XCD write ping-pong.
__global__ __launch_bounds__(256) void k_sortedges_part(const int* __restrict__ src,
                                                        const int* __restrict__ dst,
                                                        int* __restrict__ cursor,
                                                        int* __restrict__ ssrc,
                                                        int N, int E) {
    int part = blockIdx.x & (NPART - 1);
    int psz0 = (N + NPART - 1) / NPART;
    int base = part * psz0;
    int psize = min(psz0, N - base);
    int bpp = gridDim.x >> 3;
    int bi = blockIdx.x >> 3;
    for (long e = (long)bi * 256 + threadIdx.x; e < E; e += (long)bpp * 256) {
        int d = dst[e];
        int r = d - base;
        if ((unsigned)r < (unsigned)psize) {
            int pos = atomicAdd(&cursor[d], 1);
            ssrc[pos] = src[e];
        }
    }
}

// GEMM: hw = in @ W  (N x K @ K x 64). One wave per row; W staged in LDS.
template <int K>
__global__ __launch_bounds__(256) void k_gemm(const float* __restrict__ in,
                                              const float* __restrict__ W,
                                              float* __restrict__ hw, int N) {
    __shared__ float Wl[K * 64];
    __shared__ float xr[4][K];
    int tid = threadIdx.x;
    for (int i = tid; i < K * 64; i += 256) Wl[i] = W[i];
    __syncthreads();
    int lane = tid & 63;
    int wv = tid >> 6;
    int stride = gridDim.x * 4;
    for (int row = blockIdx.x * 4 + wv; row < N; row += stride) {
        for (int k = lane; k < K; k += 64) xr[wv][k] = in[(long)row * K + k];
        float acc = 0.0f;
#pragma unroll
        for (int k = 0; k < K; ++k) acc += xr[wv][k] * Wl[k * 64 + lane];
        hw[(long)row * 64 + lane] = acc;
    }
}

// CSR gather: out[d] = sum_in-edges hw[s]*dinv[s]*dinv[d] + hw[d]*snorm + b
// (+optional relu). One wave per dst node; lane = feature. dinv[s] is a
// lane-uniform broadcast load (dinv: 200KB, L2-resident).
__global__ __launch_bounds__(256) void k_gather(const float* __restrict__ hw,
                                                const int* __restrict__ ssrc,
                                                const int* __restrict__ off,
                                                const float* __restrict__ dinv,
                                                const float* __restrict__ b,
                                                float* __restrict__ outb,
                                                int N, int do_relu) {
    int wid = blockIdx.x * 4 + (threadIdx.x >> 6);
    int lane = threadIdx.x & 63;
    if (wid >= N) return;
    int j0 = off[wid], j1 = off[wid + 1];
    float di = dinv[wid];
    float acc0 = hw[(long)wid * 64 + lane] * (di * di) + b[lane];
    float acc1 = 0.0f;
    int j = j0;
    for (; j + 3 < j1; j += 4) {
        int s0 = ssrc[j], s1 = ssrc[j + 1], s2 = ssrc[j + 2], s3 = ssrc[j + 3];
        float d0 = dinv[s0], d1 = dinv[s1], d2 = dinv[s2], d3 = dinv[s3];
        float v0 = hw[(long)s0 * 64 + lane];
        float v1 = hw[(long)s1 * 64 + lane];
        float v2 = hw[(long)s2 * 64 + lane];
        float v3 = hw[(long)s3 * 64 + lane];
        acc0 += v0 * (d0 * di);
        acc1 += v1 * (d1 * di);
        acc0 += v2 * (d2 * di);
        acc1 += v3 * (d3 * di);
    }
    for (; j < j1; ++j) {
        int s = ssrc[j];
        acc0 += hw[(long)s * 64 + lane] * (dinv[s] * di);
    }
    float acc = acc0 + acc1;
    if (do_relu) acc = fmaxf(acc, 0.0f);
    outb[(long)wid * 64 + lane] = acc;
}

// relu + mean-pool: batch is SORTED; each wave owns a contiguous node range,
// register-accumulates, flushes one atomicAdd per graph transition.
__global__ __launch_bounds__(256) void k_relu_pool(const float* __restrict__ agg,
                                                   const int* __restrict__ batch,
                                                   float* __restrict__ pooled,
                                                   float* __restrict__ counts,
                                                   int N, int rows_per_wave) {
    int wid = blockIdx.x * (blockDim.x >> 6) + (threadIdx.x >> 6);
    int lane = threadIdx.x & 63;
    int i0 = wid * rows_per_wave;
    if (i0 >= N) return;
    int i1 = min(i0 + rows_per_wave, N);
    int cur = batch[i0];
    float acc = 0.0f, cnt = 0.0f;
    for (int i = i0; i < i1; ++i) {
        int g = batch[i];
        if (g != cur) {
            atomicAdd(&pooled[cur * 64 + lane], acc);
            if (lane == 0) atomicAdd(&counts[cur], cnt);
            acc = 0.0f; cnt = 0.0f; cur = g;
        }
        acc += fmaxf(agg[(long)i * 64 + lane], 0.0f);
        cnt += 1.0f;
    }
    atomicAdd(&pooled[cur * 64 + lane], acc);
    if (lane == 0) atomicAdd(&counts[cur], cnt);
}

__global__ void k_pool_div(float* pooled, const float* counts) {
    int i = blockIdx.x * blockDim.x + threadIdx.x;
    if (i < NG * HID) {
        float c = fmaxf(counts[i >> 6], 1.0f);
        pooled[i] /= c;
    }
}

// mu / logvar heads -> out[900 + idx]
__global__ void k_heads(const float* __restrict__ pooled,
                        const float* __restrict__ Wmu, const float* __restrict__ bmu,
                        const float* __restrict__ Wlv, const float* __restrict__ blv,
                        float* __restrict__ out) {
    int idx = blockIdx.x * blockDim.x + threadIdx.x;
    if (idx >= 2 * NG * LAT) return;
    int which = idx >> 11;          // 0: mu, 1: logvar
    int r = idx & (NG * LAT - 1);
    int g = r >> 5, l = r & 31;
    const float* W = which ? Wlv : Wmu;
    const float* b = which ? blv : bmu;
    float s = b[l];
#pragma unroll 8
    for (int h = 0; h < HID; ++h) s += pooled[g * 64 + h] * W[h * 32 + l];
    out[900 + idx] = s;
}

// Decoder stage 1: 30 blocks x 64 threads; parallelizes Wl2/We1 reads.
__global__ __launch_bounds__(64) void k_dec1(const float* __restrict__ Wl1,
                                             const float* __restrict__ bl1,
                                             const float* __restrict__ Wl2,
                                             const float* __restrict__ bl2,
                                             const float* __restrict__ We1,
                                             const float* __restrict__ out,
                                             float* __restrict__ hi,
                                             float* __restrict__ hj) {
    __shared__ float z0[LAT];
    __shared__ float hr[HID];
    __shared__ float em[HID];
    int tid = threadIdx.x;
    int n = blockIdx.x;
    if (tid < LAT) z0[tid] = out[900 + tid];  // mu row of graph 0
    __syncthreads();
    float s = bl1[tid];
#pragma unroll
    for (int l = 0; l < LAT; ++l) s += z0[l] * Wl1[l * HID + tid];
    hr[tid] = fmaxf(s, 0.0f);
    __syncthreads();
    float e = bl2[n * HID + tid];
#pragma unroll 8
    for (int h = 0; h < HID; ++h) e += hr[h] * Wl2[h * (HID * MAXN) + n * HID + tid];
    em[tid] = e;
    __syncthreads();
    float a = 0.0f, bb = 0.0f;
#pragma unroll 8
    for (int f = 0; f < HID; ++f) {
        float ev = em[f];
        a += ev * We1[f * HID + tid];
        bb += ev * We1[(HID + f) * HID + tid];
    }
    hi[n * HID + tid] = a;
    hj[n * HID + tid] = bb;
}

// Decoder stage 2: single block, adj from LDS-staged hi/hj (stride-65 pad).
__global__ __launch_bounds__(256) void k_dec2(const float* __restrict__ hi,
                                              const float* __restrict__ hj,
                                              const float* __restrict__ be1,
                                              const float* __restrict__ We2,
                                              const float* __restrict__ be2,
                                              float* __restrict__ out) {
    __shared__ float shi[MAXN * 65];
    __shared__ float shj[MAXN * 65];
    __shared__ float sbe[HID];
    __shared__ float sw[HID];
    int tid = threadIdx.x;
    for (int i = tid; i < MAXN * HID; i += 256) {
        int n = i >> 6, k = i & 63;
        shi[n * 65 + k] = hi[i];
        shj[n * 65 + k] = hj[i];
    }
    if (tid < HID) { sbe[tid] = be1[tid]; sw[tid] = We2[tid]; }
    __syncthreads();
    float bias2 = be2[0];
    for (int idx = tid; idx < MAXN * MAXN; idx += 256) {
        int i = idx / MAXN, j = idx % MAXN;
        if (i == j) { out[idx] = 0.0f; continue; }
        int a = i < j ? i : j;
        int b = i < j ? j : i;
        float s = bias2;
#pragma unroll 8
        for (int k = 0; k < HID; ++k)
            s += fmaxf(shi[a * 65 + k] + shj[b * 65 + k] + sbe[k], 0.0f) * sw[k];
        out[idx] = 1.0f / (1.0f + expf(-s));
    }
}

extern "C" void kernel_launch(void* const* d_in, const int* in_sizes, int n_in,
                              void* d_out, int out_size, void* d_ws, size_t ws_size,
                              hipStream_t stream) {
    const float* x = (const float*)d_in[0];
    const int* ei = (const int*)d_in[1];
    const int* batch = (const int*)d_in[2];
    const float* W1 = (const float*)d_in[4];
    const float* b1 = (const float*)d_in[5];
    const float* W2 = (const float*)d_in[6];
    const float* b2 = (const float*)d_in[7];
    const float* Wmu = (const float*)d_in[8];
    const float* bmu = (const float*)d_in[9];
    const float* Wlv = (const float*)d_in[10];
    const float* blv = (const float*)d_in[11];
    const float* Wl1 = (const float*)d_in[12];
    const float* bl1 = (const float*)d_in[13];
    const float* Wl2 = (const float*)d_in[14];
    const float* bl2 = (const float*)d_in[15];
    const float* We1 = (const float*)d_in[16];
    const float* be1 = (const float*)d_in[17];
    const float* We2 = (const float*)d_in[18];
    const float* be2 = (const float*)d_in[19];

    const int N = in_sizes[2];            // 50000
    const int E = in_sizes[1] / 2;        // 800000
    const int* src = ei;
    const int* dst = ei + E;

    // workspace carve-up, 256B aligned
    char* ws = (char*)d_ws;
    size_t off_b = 0;
    auto alloc = [&](size_t nbytes) {
        void* p = (void*)(ws + off_b);
        off_b = (off_b + nbytes + 255) & ~(size_t)255;
        return p;
    };
    float* dinv   = (float*)alloc((size_t)N * 4);
    float* bufA   = (float*)alloc((size_t)N * 64 * 4);  // h1 / agg2
    float* bufB   = (float*)alloc((size_t)N * 64 * 4);  // hw1 / hw2
    float* pooled = (float*)alloc((NG * HID + NG) * 4); // pooled | counts contiguous
    float* counts = pooled + NG * HID;
    int*   hist   = (int*)alloc((size_t)N * 4);
    int*   incl   = (int*)alloc((size_t)N * 4);
    int*   bsum   = (int*)alloc(128 * 4);
    int*   offs   = (int*)alloc(((size_t)N + 1) * 4);
    int*   cursor = (int*)alloc((size_t)N * 4);
    int*   ssrc   = (int*)alloc((size_t)E * 4);
    float* dhi    = (float*)alloc(MAXN * HID * 4);
    float* dhj    = (float*)alloc(MAXN * HID * 4);

    float* out = (float*)d_out;
    const int nb_scan = (N + SCAN_CHUNK - 1) / SCAN_CHUNK;  // 98

    // 1) CSR build: hist -> scan -> offsets/dinv -> partitioned bucket fill
    k_zero_i<<<(N + 255) / 256, 256, 0, stream>>>(hist, N);
    k_hist_part<<<2048, 256, 0, stream>>>(dst, hist, N, E);
    k_scan1<<<nb_scan, SCAN_CHUNK, 0, stream>>>(hist, incl, bsum, N);
    k_scan_top<<<1, 128, 0, stream>>>(bsum, nb_scan);
    k_scan_add<<<(N + 255) / 256, 256, 0, stream>>>(hist, incl, bsum, offs, cursor, dinv, N, E);
    k_sortedges_part<<<1024, 256, 0, stream>>>(src, dst, cursor, ssrc, N, E);

    // zero pooled + counts (contiguous)
    k_zero_f<<<(NG * HID + NG + 255) / 256, 256, 0, stream>>>(pooled, NG * HID + NG);

    // 2) layer 1: hw1 = x@W1 ; h1 = relu(gather)
    k_gemm<FEAT><<<2048, 256, 0, stream>>>(x, W1, bufB, N);
    k_gather<<<(N + 3) / 4, 256, 0, stream>>>(bufB, ssrc, offs, dinv, b1, bufA, N, 1);

    // 3) layer 2: hw2 = h1@W2 ; agg2 = gather (relu deferred to pool)
    k_gemm<HID><<<2048, 256, 0, stream>>>(bufA, W2, bufB, N);
    k_gather<<<(N + 3) / 4, 256, 0, stream>>>(bufB, ssrc, offs, dinv, b2, bufA, N, 0);

    // 4) relu + mean-pool (contiguous ranges, register accumulation)
    {
        const int waves = 2048;
        int rpw = (N + waves - 1) / waves;
        k_relu_pool<<<512, 256, 0, stream>>>(bufA, batch, pooled, counts, N, rpw);
    }
    k_pool_div<<<(NG * HID + 255) / 256, 256, 0, stream>>>(pooled, counts);

    // 5) mu / logvar -> out[900:]
    k_heads<<<(2 * NG * LAT + 255) / 256, 256, 0, stream>>>(pooled, Wmu, bmu, Wlv, blv, out);

    // 6) decoder -> out[0:900]
    k_dec1<<<MAXN, 64, 0, stream>>>(Wl1, bl1, Wl2, bl2, We1, out, dhi, dhj);
    k_dec2<<<1, 256, 0, stream>>>(dhi, dhj, be1, We2, be2, out);
}

// Round 7
// 247.072 us; speedup vs baseline: 1.1647x; 1.0515x over previous
//
#include <hip/hip_runtime.h>
#include <hip/hip_bf16.h>
#include <math.h>

// Problem constants (from reference)
#define FEAT 128
#define HID 64
#define LAT 32
#define NG 64
#define MAXN 30
#define SCAN_CHUNK 512
#define NPART 8
// out layout: adj (30*30=900) | mu (64*32=2048) | logvar (2048)

typedef __hip_bfloat16 bf16;

__global__ void k_zero_w(int* p, int n) {   // zero n 4-byte words
    int i = blockIdx.x * blockDim.x + threadIdx.x;
    if (i < n) p[i] = 0;
}

// Partitioned in-degree histogram, DIRECT global atomics (no LDS):
// partition p = blockIdx&7 -> XCD p by round-robin dispatch; p owns dst range
// [base,lim) -> hist lines RMW'd by one XCD only, no cross-XCD bouncing.
__global__ __launch_bounds__(256) void k_hist_part(const int* __restrict__ dst,
                                                   int* __restrict__ hist,
                                                   int N, int E) {
    int part = blockIdx.x & (NPART - 1);
    int psz0 = (N + NPART - 1) / NPART;
    int base = part * psz0;
    int lim = min(base + psz0, N);
    int bpp = gridDim.x >> 3;
    int bi = blockIdx.x >> 3;
    for (long e = (long)bi * 256 + threadIdx.x; e < E; e += (long)bpp * 256) {
        int d = dst[e];
        if (d >= base && d < lim) atomicAdd(&hist[d], 1);
    }
}

// block-level inclusive scan (Hillis-Steele), chunk = 512
__global__ __launch_bounds__(SCAN_CHUNK) void k_scan1(const int* __restrict__ hist,
                                                      int* __restrict__ incl,
                                                      int* __restrict__ bsum, int N) {
    __shared__ int buf[SCAN_CHUNK];
    int i = blockIdx.x * SCAN_CHUNK + threadIdx.x;
    int v = (i < N) ? hist[i] : 0;
    buf[threadIdx.x] = v;
    __syncthreads();
    for (int d = 1; d < SCAN_CHUNK; d <<= 1) {
        int t = (threadIdx.x >= d) ? buf[threadIdx.x - d] : 0;
        __syncthreads();
        buf[threadIdx.x] += t;
        __syncthreads();
    }
    if (i < N) incl[i] = buf[threadIdx.x];
    if (threadIdx.x == SCAN_CHUNK - 1) bsum[blockIdx.x] = buf[threadIdx.x];
}

// scan of block sums (single block, up to 128 blocks) -> exclusive
__global__ __launch_bounds__(128) void k_scan_top(int* bsum, int nb) {
    __shared__ int buf[128];
    int v = (threadIdx.x < nb) ? bsum[threadIdx.x] : 0;
    buf[threadIdx.x] = v;
    __syncthreads();
    for (int d = 1; d < 128; d <<= 1) {
        int t = (threadIdx.x >= d) ? buf[threadIdx.x - d] : 0;
        __syncthreads();
        buf[threadIdx.x] += t;
        __syncthreads();
    }
    if (threadIdx.x < nb) bsum[threadIdx.x] = buf[threadIdx.x] - v;  // exclusive
}

// finalize: exclusive offsets, cursor copy, dinv = rsqrt(1 + indeg)
__global__ void k_scan_add(const int* __restrict__ hist, const int* __restrict__ incl,
                           const int* __restrict__ bsum, int* __restrict__ off,
                           int* __restrict__ cursor, float* __restrict__ dinv,
                           int N, int E) {
    int i = blockIdx.x * blockDim.x + threadIdx.x;
    if (i < N) {
        int h = hist[i];
        int o = incl[i] - h + bsum[i / SCAN_CHUNK];
        off[i] = o;
        cursor[i] = o;
        dinv[i] = rsqrtf(1.0f + (float)h);
    }
    if (i == 0) off[N] = E;
}

// Partitioned bucket-fill: partition p (blockIdx&7 -> XCD p) handles its dst
// range only -> CSR region written by one XCD, no cross-XCD write ping-pong.
__global__ __launch_bounds__(256) void k_sortedges_part(const int* __restrict__ src,
                                                        const int* __restrict__ dst,
                                                        int* __restrict__ cursor,
                                                        int* __restrict__ ssrc,
                                                        int N, int E) {
    int part = blockIdx.x & (NPART - 1);
    int psz0 = (N + NPART - 1) / NPART;
    int base = part * psz0;
    int psize = min(psz0, N - base);
    int bpp = gridDim.x >> 3;
    int bi = blockIdx.x >> 3;
    for (long e = (long)bi * 256 + threadIdx.x; e < E; e += (long)bpp * 256) {
        int d = dst[e];
        int r = d - base;
        if ((unsigned)r < (unsigned)psize) {
            int pos = atomicAdd(&cursor[d], 1);
            ssrc[pos] = src[e];
        }
    }
}

// GEMM: hw = bf16(in @ W)  (N x K @ K x 64). One wave per row; W in LDS.
// bf16 output halves the gather-side row traffic (huge accuracy headroom:
// threshold 9.7e-3 vs f32 absmax 1.9e-6).
template <int K>
__global__ __launch_bounds__(256) void k_gemm(const float* __restrict__ in,
                                              const float* __restrict__ W,
                                              bf16* __restrict__ hw, int N) {
    __shared__ float Wl[K * 64];
    __shared__ float xr[4][K];
    int tid = threadIdx.x;
    for (int i = tid; i < K * 64; i += 256) Wl[i] = W[i];
    __syncthreads();
    int lane = tid & 63;
    int wv = tid >> 6;
    int stride = gridDim.x * 4;
    for (int row = blockIdx.x * 4 + wv; row < N; row += stride) {
        for (int k = lane; k < K; k += 64) xr[wv][k] = in[(long)row * K + k];
        float acc = 0.0f;
#pragma unroll
        for (int k = 0; k < K; ++k) acc += xr[wv][k] * Wl[k * 64 + lane];
        hw[(long)row * 64 + lane] = __float2bfloat16(acc);
    }
}

// CSR gather: out[d] = sum_in-edges bf16(hw[s])*dinv[s]*dinv[d]
//                      + bf16(hw[d])*snorm + b   (+optional relu)
// One wave per dst node; lane = feature (2B/lane -> 128B/row).
__global__ __launch_bounds__(256) void k_gather(const bf16* __restrict__ hw,
                                                const int* __restrict__ ssrc,
                                                const int* __restrict__ off,
                                                const float* __restrict__ dinv,
                                                const float* __restrict__ b,
                                                float* __restrict__ outb,
                                                int N, int do_relu) {
    int wid = blockIdx.x * 4 + (threadIdx.x >> 6);
    int lane = threadIdx.x & 63;
    if (wid >= N) return;
    int j0 = off[wid], j1 = off[wid + 1];
    float di = dinv[wid];
    float acc0 = __bfloat162float(hw[(long)wid * 64 + lane]) * (di * di) + b[lane];
    float acc1 = 0.0f;
    int j = j0;
    for (; j + 3 < j1; j += 4) {
        int s0 = ssrc[j], s1 = ssrc[j + 1], s2 = ssrc[j + 2], s3 = ssrc[j + 3];
        float d0 = dinv[s0], d1 = dinv[s1], d2 = dinv[s2], d3 = dinv[s3];
        float v0 = __bfloat162float(hw[(long)s0 * 64 + lane]);
        float v1 = __bfloat162float(hw[(long)s1 * 64 + lane]);
        float v2 = __bfloat162float(hw[(long)s2 * 64 + lane]);
        float v3 = __bfloat162float(hw[(long)s3 * 64 + lane]);
        acc0 += v0 * (d0 * di);
        acc1 += v1 * (d1 * di);
        acc0 += v2 * (d2 * di);
        acc1 += v3 * (d3 * di);
    }
    for (; j < j1; ++j) {
        int s = ssrc[j];
        acc0 += __bfloat162float(hw[(long)s * 64 + lane]) * (dinv[s] * di);
    }
    float acc = acc0 + acc1;
    if (do_relu) acc = fmaxf(acc, 0.0f);
    outb[(long)wid * 64 + lane] = acc;
}

// relu + mean-pool: batch is SORTED; each wave owns a contiguous node range,
// register-accumulates, flushes one atomicAdd per graph transition.
__global__ __launch_bounds__(256) void k_relu_pool(const float* __restrict__ agg,
                                                   const int* __restrict__ batch,
                                                   float* __restrict__ pooled,
                                                   float* __restrict__ counts,
                                                   int N, int rows_per_wave) {
    int wid = blockIdx.x * (blockDim.x >> 6) + (threadIdx.x >> 6);
    int lane = threadIdx.x & 63;
    int i0 = wid * rows_per_wave;
    if (i0 >= N) return;
    int i1 = min(i0 + rows_per_wave, N);
    int cur = batch[i0];
    float acc = 0.0f, cnt = 0.0f;
    for (int i = i0; i < i1; ++i) {
        int g = batch[i];
        if (g != cur) {
            atomicAdd(&pooled[cur * 64 + lane], acc);
            if (lane == 0) atomicAdd(&counts[cur], cnt);
            acc = 0.0f; cnt = 0.0f; cur = g;
        }
        acc += fmaxf(agg[(long)i * 64 + lane], 0.0f);
        cnt += 1.0f;
    }
    atomicAdd(&pooled[cur * 64 + lane], acc);
    if (lane == 0) atomicAdd(&counts[cur], cnt);
}

// mu / logvar heads with fused mean-divide -> out[900 + idx]
__global__ void k_heads(const float* __restrict__ pooled,
                        const float* __restrict__ counts,
                        const float* __restrict__ Wmu, const float* __restrict__ bmu,
                        const float* __restrict__ Wlv, const float* __restrict__ blv,
                        float* __restrict__ out) {
    int idx = blockIdx.x * blockDim.x + threadIdx.x;
    if (idx >= 2 * NG * LAT) return;
    int which = idx >> 11;          // 0: mu, 1: logvar
    int r = idx & (NG * LAT - 1);
    int g = r >> 5, l = r & 31;
    const float* W = which ? Wlv : Wmu;
    const float* b = which ? blv : bmu;
    float s = 0.0f;
#pragma unroll 8
    for (int h = 0; h < HID; ++h) s += pooled[g * 64 + h] * W[h * 32 + l];
    float c = fmaxf(counts[g], 1.0f);
    out[900 + idx] = s / c + b[l];
}

// Decoder stage 1: 30 blocks x 64 threads; parallelizes Wl2/We1 reads.
__global__ __launch_bounds__(64) void k_dec1(const float* __restrict__ Wl1,
                                             const float* __restrict__ bl1,
                                             const float* __restrict__ Wl2,
                                             const float* __restrict__ bl2,
                                             const float* __restrict__ We1,
                                             const float* __restrict__ out,
                                             float* __restrict__ hi,
                                             float* __restrict__ hj) {
    __shared__ float z0[LAT];
    __shared__ float hr[HID];
    __shared__ float em[HID];
    int tid = threadIdx.x;
    int n = blockIdx.x;
    if (tid < LAT) z0[tid] = out[900 + tid];  // mu row of graph 0
    __syncthreads();
    float s = bl1[tid];
#pragma unroll
    for (int l = 0; l < LAT; ++l) s += z0[l] * Wl1[l * HID + tid];
    hr[tid] = fmaxf(s, 0.0f);
    __syncthreads();
    float e = bl2[n * HID + tid];
#pragma unroll 8
    for (int h = 0; h < HID; ++h) e += hr[h] * Wl2[h * (HID * MAXN) + n * HID + tid];
    em[tid] = e;
    __syncthreads();
    float a = 0.0f, bb = 0.0f;
#pragma unroll 8
    for (int f = 0; f < HID; ++f) {
        float ev = em[f];
        a += ev * We1[f * HID + tid];
        bb += ev * We1[(HID + f) * HID + tid];
    }
    hi[n * HID + tid] = a;
    hj[n * HID + tid] = bb;
}

// Decoder stage 2: single block, adj from LDS-staged hi/hj (stride-65 pad).
__global__ __launch_bounds__(256) void k_dec2(const float* __restrict__ hi,
                                              const float* __restrict__ hj,
                                              const float* __restrict__ be1,
                                              const float* __restrict__ We2,
                                              const float* __restrict__ be2,
                                              float* __restrict__ out) {
    __shared__ float shi[MAXN * 65];
    __shared__ float shj[MAXN * 65];
    __shared__ float sbe[HID];
    __shared__ float sw[HID];
    int tid = threadIdx.x;
    for (int i = tid; i < MAXN * HID; i += 256) {
        int n = i >> 6, k = i & 63;
        shi[n * 65 + k] = hi[i];
        shj[n * 65 + k] = hj[i];
    }
    if (tid < HID) { sbe[tid] = be1[tid]; sw[tid] = We2[tid]; }
    __syncthreads();
    float bias2 = be2[0];
    for (int idx = tid; idx < MAXN * MAXN; idx += 256) {
        int i = idx / MAXN, j = idx % MAXN;
        if (i == j) { out[idx] = 0.0f; continue; }
        int a = i < j ? i : j;
        int b = i < j ? j : i;
        float s = bias2;
#pragma unroll 8
        for (int k = 0; k < HID; ++k)
            s += fmaxf(shi[a * 65 + k] + shj[b * 65 + k] + sbe[k], 0.0f) * sw[k];
        out[idx] = 1.0f / (1.0f + expf(-s));
    }
}

extern "C" void kernel_launch(void* const* d_in, const int* in_sizes, int n_in,
                              void* d_out, int out_size, void* d_ws, size_t ws_size,
                              hipStream_t stream) {
    const float* x = (const float*)d_in[0];
    const int* ei = (const int*)d_in[1];
    const int* batch = (const int*)d_in[2];
    const float* W1 = (const float*)d_in[4];
    const float* b1 = (const float*)d_in[5];
    const float* W2 = (const float*)d_in[6];
    const float* b2 = (const float*)d_in[7];
    const float* Wmu = (const float*)d_in[8];
    const float* bmu = (const float*)d_in[9];
    const float* Wlv = (const float*)d_in[10];
    const float* blv = (const float*)d_in[11];
    const float* Wl1 = (const float*)d_in[12];
    const float* bl1 = (const float*)d_in[13];
    const float* Wl2 = (const float*)d_in[14];
    const float* bl2 = (const float*)d_in[15];
    const float* We1 = (const float*)d_in[16];
    const float* be1 = (const float*)d_in[17];
    const float* We2 = (const float*)d_in[18];
    const float* be2 = (const float*)d_in[19];

    const int N = in_sizes[2];            // 50000
    const int E = in_sizes[1] / 2;        // 800000
    const int* src = ei;
    const int* dst = ei + E;

    // workspace carve-up, 256B aligned
    char* ws = (char*)d_ws;
    size_t off_b = 0;
    auto alloc = [&](size_t nbytes) {
        void* p = (void*)(ws + off_b);
        off_b = (off_b + nbytes + 255) & ~(size_t)255;
        return p;
    };
    float* dinv   = (float*)alloc((size_t)N * 4);
    float* bufA   = (float*)alloc((size_t)N * 64 * 4);        // h1 / agg2 (f32)
    bf16*  hwb    = (bf16*)alloc((size_t)N * 64 * 2);         // hw1 / hw2 (bf16)
    // contiguous zero region: pooled | counts | hist
    float* pooled = (float*)alloc((NG * HID + NG + (size_t)N) * 4);
    float* counts = pooled + NG * HID;
    int*   hist   = (int*)(counts + NG);
    int*   incl   = (int*)alloc((size_t)N * 4);
    int*   bsum   = (int*)alloc(128 * 4);
    int*   offs   = (int*)alloc(((size_t)N + 1) * 4);
    int*   cursor = (int*)alloc((size_t)N * 4);
    int*   ssrc   = (int*)alloc((size_t)E * 4);
    float* dhi    = (float*)alloc(MAXN * HID * 4);
    float* dhj    = (float*)alloc(MAXN * HID * 4);

    float* out = (float*)d_out;
    const int nb_scan = (N + SCAN_CHUNK - 1) / SCAN_CHUNK;  // 98
    const int nzero = NG * HID + NG + N;

    // 0) one zero pass for pooled|counts|hist
    k_zero_w<<<(nzero + 255) / 256, 256, 0, stream>>>((int*)pooled, nzero);

    // 1) CSR build: hist -> scan -> offsets/dinv -> partitioned bucket fill
    k_hist_part<<<2048, 256, 0, stream>>>(dst, hist, N, E);
    k_scan1<<<nb_scan, SCAN_CHUNK, 0, stream>>>(hist, incl, bsum, N);
    k_scan_top<<<1, 128, 0, stream>>>(bsum, nb_scan);
    k_scan_add<<<(N + 255) / 256, 256, 0, stream>>>(hist, incl, bsum, offs, cursor, dinv, N, E);
    k_sortedges_part<<<1024, 256, 0, stream>>>(src, dst, cursor, ssrc, N, E);

    // 2) layer 1: hw1 = bf16(x@W1) ; h1 = relu(gather)
    k_gemm<FEAT><<<2048, 256, 0, stream>>>(x, W1, hwb, N);
    k_gather<<<(N + 3) / 4, 256, 0, stream>>>(hwb, ssrc, offs, dinv, b1, bufA, N, 1);

    // 3) layer 2: hw2 = bf16(h1@W2) ; agg2 = gather (relu deferred to pool)
    k_gemm<HID><<<2048, 256, 0, stream>>>(bufA, W2, hwb, N);
    k_gather<<<(N + 3) / 4, 256, 0, stream>>>(hwb, ssrc, offs, dinv, b2, bufA, N, 0);

    // 4) relu + mean-pool (contiguous ranges, register accumulation)
    {
        const int waves = 2048;
        int rpw = (N + waves - 1) / waves;
        k_relu_pool<<<512, 256, 0, stream>>>(bufA, batch, pooled, counts, N, rpw);
    }

    // 5) mu / logvar (fused mean-divide) -> out[900:]
    k_heads<<<(2 * NG * LAT + 255) / 256, 256, 0, stream>>>(pooled, counts, Wmu, bmu, Wlv, blv, out);

    // 6) decoder -> out[0:900]
    k_dec1<<<MAXN, 64, 0, stream>>>(Wl1, bl1, Wl2, bl2, We1, out, dhi, dhj);
    k_dec2<<<1, 256, 0, stream>>>(dhi, dhj, be1, We2, be2, out);
}